// Round 10
// baseline (98.436 us; speedup 1.0000x reference)
//
#include <hip/hip_runtime.h>
#include <stdint.h>

#define BB 32
#define NN 8000
#define MM 256
#define LL (NN + MM)        // 8256
#define NSAMP 512
#define MAXPOS 128
#define T2 1024
#define CH ((LL + T2 - 1) / T2)   // 9
#define GA 8                      // gaug row stride (floats)
#define UTHR 0x3EAAAA80u          // ~0.333331 < fl(1/3): below -> q<0.5 certain

// forbid fp-contract across this value (exact-path: match numpy rounding)
__device__ __forceinline__ void opaquef(float& x) { asm("" : "+v"(x)); }

// exact reference semantics over all MM gts (serial, IEEE div) -- rare
__device__ __noinline__ void serial_exact(const float4 bx, const float a1,
                                          const float* __restrict__ ga,
                                          int* outIdx, float* outQ)
{
    float qb = -1.0f; int bi = 0;
    for (int m = 0; m < MM; ++m) {
        float gy0 = ga[m * GA + 0], gx0 = ga[m * GA + 1];
        float gy1 = ga[m * GA + 2], gx1 = ga[m * GA + 3];
        float a2  = ga[m * GA + 4];
        float ih = fmaxf(fminf(bx.z, gy1) - fmaxf(bx.x, gy0), 0.0f);
        float iw = fmaxf(fminf(bx.w, gx1) - fmaxf(bx.y, gx0), 0.0f);
        float inter = ih * iw; opaquef(inter);
        float uni = (a1 + a2) - inter;            // numpy op order/rounding
        float q = (uni > 0.0f) ? (inter / uni) : 0.0f;
        if (q > qb) { qb = q; bi = m; }
    }
    *outIdx = bi; *outQ = qb;
}

// ---------------- kernel 0: augment gts with precomputed area --------------
__global__ __launch_bounds__(256) void prep_kernel(
    const float* __restrict__ gt, float* __restrict__ gaug)
{
    const int b = blockIdx.x, m = threadIdx.x;
    float4 v = ((const float4*)(gt + (size_t)b * MM * 4))[m];
    float* ga = gaug + ((size_t)b * MM + m) * GA;
    *(float4*)ga = v;
    ga[4] = (v.z - v.x) * (v.w - v.y);   // exact fl((z-x)*(w-y)); invalid -> 0
}

// ---------------- kernel 1: per-(b,l) argmax over all 256 gts --------------
// gt data is WAVE-UNIFORM: read via uniform address -> scalar loads (SMEM),
// zero LDS / vector-memory in the inner loop (LDS pipe was the saturated
// resource, R5/R9 evidence). Rank by u = inter/(a1+a2) (monotone in IoU).
// Fast key = raw f32 bits of utilde = inter*rcp(s) (rel err ~2.5 ulp).
// Track best/sec/idx; idx by strict > (first-argmax on equal keys).
// Redo (exact serial) iff best >= UTHR && best-sec <= 32 ulp:
//   - below UTHR the true q < 0.5 for winner AND all near-ties -> row is
//     background; its midx/class are nulled downstream -> any near-tie
//     resolution is output-invisible. Class always from an EXACT
//     reference-rounded IoU division of the selected winner.
//   - the 0.5-boundary swap case (rounded-q max != u-argmax) requires
//     u-gap < ~2 ulp -> caught by the 32-ulp redo band.
// Zero-overlap rows: all keys 0 -> idx 0; exact q of gt[0] -> background ✓.
__global__ __launch_bounds__(256) void match_kernel(
    const float* __restrict__ boxes, const float* __restrict__ gaug,
    uint16_t* __restrict__ pk)
{
    const int b = blockIdx.y;
    const int l = blockIdx.x * 256 + threadIdx.x;
    if (l >= LL) return;
    const float* ga = gaug + (size_t)b * MM * GA;

    float4 bx = (l < NN) ? ((const float4*)(boxes + (size_t)b * NN * 4))[l]
                         : *(const float4*)(ga + (size_t)(l - NN) * GA);
    const bool binv = fmaxf(fmaxf(bx.x, bx.y), fmaxf(bx.z, bx.w)) < 0.0f;
    float a1 = (bx.z - bx.x) * (bx.w - bx.y); opaquef(a1);

    uint32_t best = 0, sec = 0; int idx = 0;
    #pragma unroll 4
    for (int m = 0; m < MM; ++m) {
        float gy0 = ga[m * GA + 0], gx0 = ga[m * GA + 1];
        float gy1 = ga[m * GA + 2], gx1 = ga[m * GA + 3];
        float a2  = ga[m * GA + 4];
        float ih = fmaxf(fminf(bx.z, gy1) - fmaxf(bx.x, gy0), 0.0f);
        float iw = fmaxf(fminf(bx.w, gx1) - fmaxf(bx.y, gx0), 0.0f);
        float inter = ih * iw;
        float s = fmaxf(a1 + a2, 1e-30f);          // 0/0 -> 0, never NaN
        float u = inter * __builtin_amdgcn_rcpf(s);
        uint32_t key = __float_as_uint(u);
        bool win = key > best;
        uint32_t lose = win ? best : key;          // min(best,key)
        sec  = max(sec, lose);
        best = max(best, key);
        idx  = win ? m : idx;
    }

    int cls, midx;
    if (binv) {
        cls = 2; midx = 0;        // all sim == -1 -> invalid, argmax = 0
    } else if (best >= UTHR && (best - sec) <= 32u) {
        float qb;                 // rare: exact reference semantics
        serial_exact(bx, a1, ga, &midx, &qb);
        cls = (qb >= 0.5f) ? 1 : 0;
    } else {
        midx = idx;               // one exact reference-rounded IoU for class
        float gy0 = ga[midx * GA + 0], gx0 = ga[midx * GA + 1];
        float gy1 = ga[midx * GA + 2], gx1 = ga[midx * GA + 3];
        float a2  = ga[midx * GA + 4];
        float ih = fmaxf(fminf(bx.z, gy1) - fmaxf(bx.x, gy0), 0.0f);
        float iw = fmaxf(fminf(bx.w, gx1) - fmaxf(bx.y, gx0), 0.0f);
        float inter = ih * iw; opaquef(inter);
        float uni = (a1 + a2) - inter;             // numpy op order/rounding
        float q = (uni > 0.0f) ? (inter / uni) : 0.0f;   // exact IEEE div
        cls = (q >= 0.5f) ? 1 : 0;   // searchsorted([0,.5,.5], right)
    }
    pk[(size_t)b * LL + l] = (uint16_t)(cls | (midx << 2));
}

// ---------------- scans ----------------
__device__ __forceinline__ int block_exscan_fast(int v, int* wt, int tid)
{
    const int lane = tid & 63, w = tid >> 6;
    int x = v;
    #pragma unroll
    for (int off = 1; off < 64; off <<= 1) {
        int y = __shfl_up(x, off);
        if (lane >= off) x += y;
    }
    if (lane == 63) wt[w] = x;
    __syncthreads();
    if (tid < 64) {
        int t = (tid < 16) ? wt[tid] : 0;
        #pragma unroll
        for (int off = 1; off < 16; off <<= 1) {
            int y = __shfl_up(t, off);
            if (tid >= off) t += y;
        }
        if (tid < 16) wt[tid] = t;
    }
    __syncthreads();
    return ((w > 0) ? wt[w - 1] : 0) + x - v;
}

__device__ __forceinline__ int block_exscan_seg4(int v, int* wt, int tid)
{
    const int lane = tid & 63, w = tid >> 6;
    int x = v;
    #pragma unroll
    for (int off = 1; off < 64; off <<= 1) {
        int y = __shfl_up(x, off);
        if (lane >= off) x += y;
    }
    if (lane == 63) wt[w] = x;
    __syncthreads();
    if (tid < 16) {
        int t = wt[tid];
        #pragma unroll
        for (int off = 1; off < 4; off <<= 1) {
            int y = __shfl_up(t, off);
            if ((tid & 3) >= off) t += y;
        }
        wt[tid] = t;
    }
    __syncthreads();
    return (((w & 3) > 0) ? wt[w - 1] : 0) + x - v;
}

// ---------------- kernel 2: per-batch sampling + gather --------------------
// s_pk bit layout: [1:0] cls, [9:2] matched gt idx, [15] sel flag
__global__ __launch_bounds__(T2) void sample_kernel(
    const float* __restrict__ boxes, const float* __restrict__ gt,
    const int* __restrict__ gtc, const float* __restrict__ rnd,
    const uint16_t* __restrict__ pk, float* __restrict__ out)
{
    __shared__ uint32_t s_key[LL];
    __shared__ uint16_t s_pk[LL];
    __shared__ int s_hist[512];
    __shared__ int s_warp[16];
    __shared__ int s_idx[NSAMP];
    __shared__ int s_sb[8];
    const int b = blockIdx.x, tid = threadIdx.x, lane = tid & 63;
    const float4* bb4 = (const float4*)(boxes + (size_t)b * NN * 4);
    const float4* gb4 = (const float4*)(gt + (size_t)b * MM * 4);

    if (tid == 0) s_sb[0] = 0;
    __syncthreads();

    int loc = 0;
    for (int l = tid; l < LL; l += T2) {
        s_key[l] = __float_as_uint(rnd[(size_t)b * LL + l]);
        uint16_t p = pk[(size_t)b * LL + l];
        s_pk[l] = p;
        int c = p & 3;
        loc += (c == 0) ? 1 : ((c == 1) ? 0x10000 : 0);
    }
    #pragma unroll
    for (int off = 32; off; off >>= 1) loc += __shfl_xor(loc, off);
    if (lane == 0) atomicAdd(&s_sb[0], loc);
    __syncthreads();
    const int Nn = s_sb[0] & 0xFFFF, P = s_sb[0] >> 16;

    const int posK = (P < MAXPOS) ? P : MAXPOS;
    const int negK = NSAMP - posK;
    const bool negRad = (Nn > negK);
    const bool posRad = (P > MAXPOS);

    uint32_t prefix0 = 0, prefix1 = 0;
    int rem0 = negK, rem1 = MAXPOS;
    if (negRad || posRad) {
        for (int round = 0; round < 4; ++round) {
            const int shift = 24 - 8 * round;
            if (tid < 512) s_hist[tid] = 0;
            __syncthreads();
            const uint32_t pmask = (round == 0) ? 0u : (0xFFFFFFFFu << (shift + 8));
            for (int l = tid; l < LL; l += T2) {
                const uint32_t k = s_key[l];
                const int c = s_pk[l] & 3;
                bool doit = (c == 0) ? (negRad && ((k & pmask) == prefix0))
                          : (c == 1) ? (posRad && ((k & pmask) == prefix1))
                          : false;
                if (doit) atomicAdd(&s_hist[(c << 8) | ((k >> shift) & 255)], 1);
            }
            __syncthreads();
            int h = 0;
            if (tid < 512) h = s_hist[(tid & 0x100) | (255 - (tid & 255))];
            const int above = block_exscan_seg4(h, s_warp, tid);
            if (tid < 512) {
                const int c = tid >> 8;
                const int rem = c ? rem1 : rem0;
                const bool act = c ? posRad : negRad;
                if (act && above < rem && above + h >= rem) {
                    s_sb[4 + c * 2] = 255 - (tid & 255);
                    s_sb[5 + c * 2] = above;
                }
            }
            __syncthreads();
            if (negRad) { prefix0 |= ((uint32_t)s_sb[4]) << shift; rem0 -= s_sb[5]; }
            if (posRad) { prefix1 |= ((uint32_t)s_sb[6]) << shift; rem1 -= s_sb[7]; }
            __syncthreads();
        }
    }
    const uint32_t thr0 = negRad ? prefix0 : 0u;  const int r0 = negRad ? rem0 : LL;
    const uint32_t thr1 = posRad ? prefix1 : 0u;  const int r1 = posRad ? rem1 : LL;

    const int lo = tid * CH, hi = (lo + CH < LL) ? (lo + CH) : LL;
    int nt = 0;
    for (int l = lo; l < hi; ++l) {
        const int c = s_pk[l] & 3;
        const uint32_t k = s_key[l];
        if (c == 0) { if (k == thr0) nt += 1; }
        else if (c == 1) { if (k == thr1) nt += 0x10000; }
    }
    const int basep = block_exscan_fast(nt, s_warp, tid);
    int base0 = basep & 0xFFFF, base1 = basep >> 16;
    for (int l = lo; l < hi; ++l) {
        const int c = s_pk[l] & 3;
        if (c > 1) continue;
        const uint32_t k = s_key[l];
        const uint32_t thr = c ? thr1 : thr0;
        bool sel = (k > thr);
        if (k == thr) {
            if (c == 0) { sel = (base0 < r0); ++base0; }
            else        { sel = (base1 < r1); ++base1; }
        }
        if (sel) s_pk[l] |= 0x8000;
    }
    __syncthreads();

    int cnt = 0;
    for (int l = lo; l < hi; ++l) cnt += (s_pk[l] & 0x8000) ? 1 : 0x10000;
    const int pb = block_exscan_fast(cnt, s_warp, tid);
    const int S = s_warp[15] & 0xFFFF;
    int bs = pb & 0xFFFF, bu = (pb >> 16) + S;
    for (int l = lo; l < hi; ++l) {
        if (s_pk[l] & 0x8000) { if (bs < NSAMP) s_idx[bs] = l; ++bs; }
        else                  { if (bu < NSAMP) s_idx[bu] = l; ++bu; }
    }
    __syncthreads();

    if (tid < NSAMP) {
        const int l = s_idx[tid];
        float4 bx = (l < NN) ? bb4[l] : gb4[l - NN];
        const int p = s_pk[l];
        const int c = p & 3, mi = (p >> 2) & 0xFF;
        const bool bg = (c != 1);          // background = matched_val < 0.5
        float4 gb = make_float4(0.f, 0.f, 0.f, 0.f);
        int cl = 0, si = -1;
        if (!bg) {
            gb = gb4[mi];
            cl = gtc[(size_t)b * MM + mi];
            si = mi;
        }
        const size_t rk = (size_t)b * NSAMP + tid;
        ((float4*)out)[rk] = bx;                                   // rois
        ((float4*)(out + (size_t)BB * NSAMP * 4))[rk] = gb;        // sampled_gt_boxes
        out[(size_t)2 * BB * NSAMP * 4 + rk] = (float)cl;          // classes
        out[(size_t)2 * BB * NSAMP * 4 + (size_t)BB * NSAMP + rk] = (float)si; // indices
    }
}

extern "C" void kernel_launch(void* const* d_in, const int* in_sizes, int n_in,
                              void* d_out, int out_size, void* d_ws, size_t ws_size,
                              hipStream_t stream)
{
    const float* boxes = (const float*)d_in[0];   // [32,8000,4] f32
    const float* gt    = (const float*)d_in[1];   // [32,256,4]  f32
    const int*   gtc   = (const int*)  d_in[2];   // [32,256]    i32
    const float* rnd   = (const float*)d_in[3];   // [32,8256]   f32
    float* out = (float*)d_out;

    float*    gaug = (float*)d_ws;                                 // 256 KB
    uint16_t* pk   = (uint16_t*)((char*)d_ws + (size_t)BB * MM * GA * 4); // 516 KB

    prep_kernel<<<BB, MM, 0, stream>>>(gt, gaug);
    dim3 g1((LL + 255) / 256, BB);                // 33,32 = 1056 blocks
    match_kernel<<<g1, 256, 0, stream>>>(boxes, gaug, pk);
    sample_kernel<<<BB, T2, 0, stream>>>(boxes, gt, gtc, rnd, pk, out);
}

// Round 11
// 72.757 us; speedup vs baseline: 1.3529x; 1.3529x over previous
//
#include <hip/hip_runtime.h>
#include <stdint.h>

#define BB 32
#define NN 8000
#define MM 256
#define LL (NN + MM)        // 8256
#define NSAMP 512
#define MAXPOS 128
#define T2 1024
#define CH ((LL + T2 - 1) / T2)   // 9
#define SPLIT 4
#define MSUB (MM / SPLIT)   // 64
#define MT 128              // match block threads (2 waves: fine scheduling)

// forbid fp-contract across this value (exact-path: match numpy rounding)
__device__ __forceinline__ void opaquef(float& x) { asm("" : "+v"(x)); }

// exact reference semantics over the compacted valid-gt list (rare fallback)
__device__ __noinline__ int serial_argmax(const float4 bx, const float a1,
                                          const float4* s_gt, const float* s_a2,
                                          int nv)
{
    float qb = -1.0f; int bi = 0;
    for (int m = 0; m < nv; ++m) {
        float4 g = s_gt[m];
        float ih = fmaxf(fminf(bx.z, g.z) - fmaxf(bx.x, g.x), 0.0f);
        float iw = fmaxf(fminf(bx.w, g.w) - fmaxf(bx.y, g.y), 0.0f);
        float inter = ih * iw; opaquef(inter);
        float uni = (a1 + s_a2[m]) - inter;
        float q = (uni > 0.0f) ? (inter / uni) : 0.0f;
        if (q > qb) { qb = q; bi = m; }
    }
    return bi;    // compacted index (ascending original order preserved)
}

__device__ __forceinline__ uint32_t approx_key(const float4 bx, float a1,
                                               const float4 g, float a2,
                                               uint32_t klo)
{
    float ih = fmaxf(fminf(bx.z, g.z) - fmaxf(bx.x, g.x), 0.0f);
    float iw = fmaxf(fminf(bx.w, g.w) - fmaxf(bx.y, g.y), 0.0f);
    float inter = ih * iw;
    float s = a1 + a2;                             // no clamp: NaN rows are
    float u = inter * __builtin_amdgcn_rcpf(s);    //  provably background
    return (__float_as_uint(u) & 0xFFFFFFC0u) | klo;
}

// ---------------- kernel 1: per-(b, box-pair, split) argmax over valid gts -
// Rank by u = inter/(a1+a2) (monotone in IoU). key = (u_bits & ~63)|(63-m):
// argmax via v_max_u32, truncated-u ties pick smaller m. Winner provably the
// reference's rounded-quotient argmax when gap > 64 ulp; <= 64 -> exact
// serial redo. Valid gts compacted (ballot); zero/NaN-key rows are provably
// background downstream -> outputs unaffected. 128-thr blocks: 4224 blocks
// (~16.5/CU) for fine scheduling (R8/R9 were latency-bound, not issue-bound).
__global__ __launch_bounds__(MT) void match_split_kernel(
    const float* __restrict__ boxes, const float* __restrict__ gt,
    uint32_t* __restrict__ keys)
{
    __shared__ float4 s_gt[MSUB];
    __shared__ float  s_a2[MSUB];
    __shared__ uint32_t s_klo[MSUB];
    __shared__ int s_nv;
    const int b = blockIdx.y, sp = blockIdx.z, tid = threadIdx.x;
    if (tid < MSUB) {   // tid 0..63 == wave 0 exactly
        float4 v = ((const float4*)(gt + ((size_t)b * MM + sp * MSUB) * 4))[tid];
        bool valid = !(fmaxf(fmaxf(v.x, v.y), fmaxf(v.z, v.w)) < 0.0f);
        uint64_t mk = __ballot(valid);
        int pos = __popcll(mk & ((1ull << tid) - 1));
        if (valid) {
            s_gt[pos] = v;
            s_a2[pos] = (v.z - v.x) * (v.w - v.y);
            s_klo[pos] = (uint32_t)(63 - tid);
        }
        if (tid == 0) s_nv = (int)__popcll(mk);
    }
    __syncthreads();
    const int l0 = blockIdx.x * (MT * 2) + tid * 2;
    if (l0 >= LL) return;
    const int l1 = l0 + 1;
    const bool v1 = (l1 < LL);
    const int l1c = v1 ? l1 : l0;
    const int nv = s_nv;

    const float4* bb4 = (const float4*)(boxes + (size_t)b * NN * 4);
    const float4* gb4 = (const float4*)(gt + (size_t)b * MM * 4);
    float4 bx0 = (l0 < NN) ? bb4[l0] : gb4[l0 - NN];
    float4 bx1 = (l1c < NN) ? bb4[l1c] : gb4[l1c - NN];
    float a10 = (bx0.z - bx0.x) * (bx0.w - bx0.y); opaquef(a10);
    float a11 = (bx1.z - bx1.x) * (bx1.w - bx1.y); opaquef(a11);

    uint32_t best0 = 0, sec0 = 0, best1 = 0, sec1 = 0;
    #pragma unroll 4
    for (int m = 0; m < nv; ++m) {
        const float4 g = s_gt[m];
        const float a2 = s_a2[m];
        const uint32_t klo = s_klo[m];
        {
            uint32_t key = approx_key(bx0, a10, g, a2, klo);
            sec0  = max(sec0, min(best0, key));
            best0 = max(best0, key);
        }
        {
            uint32_t key = approx_key(bx1, a11, g, a2, klo);
            sec1  = max(sec1, min(best1, key));
            best1 = max(best1, key);
        }
    }

    bool redo0 = ((best0 & ~63u) != 0u) &&
                 (((best0 & ~63u) - (sec0 & ~63u)) <= 64u);
    bool redo1 = v1 && ((best1 & ~63u) != 0u) &&
                 (((best1 & ~63u) - (sec1 & ~63u)) <= 64u);
    if (__any(redo0 || redo1)) {
        if (redo0) {
            int w = serial_argmax(bx0, a10, s_gt, s_a2, nv);
            best0 = approx_key(bx0, a10, s_gt[w], s_a2[w], s_klo[w]);
        }
        if (redo1) {
            int w = serial_argmax(bx1, a11, s_gt, s_a2, nv);
            best1 = approx_key(bx1, a11, s_gt[w], s_a2[w], s_klo[w]);
        }
    }
    keys[((size_t)b * LL + l0) * SPLIT + sp] = best0;
    if (v1) keys[((size_t)b * LL + l1) * SPLIT + sp] = best1;
}

// ---------------- kernel 1b: cross-split winner + classify (1056 blocks) ---
__global__ __launch_bounds__(256) void merge2_kernel(
    const float* __restrict__ boxes, const float* __restrict__ gt,
    uint32_t* __restrict__ keys)
{
    const int b = blockIdx.y;
    const int l = blockIdx.x * 256 + threadIdx.x;
    if (l >= LL) return;
    const float4* bb4 = (const float4*)(boxes + (size_t)b * NN * 4);
    const float4* gb4 = (const float4*)(gt + (size_t)b * MM * 4);
    const uint4 kv = ((const uint4*)keys)[(size_t)b * LL + l];
    float4 bx = (l < NN) ? bb4[l] : gb4[l - NN];
    int cls, midx = 0;
    if (fmaxf(fmaxf(bx.x, bx.y), fmaxf(bx.z, bx.w)) < 0.0f) {
        cls = 2;   // invalid box: all sim == -1 -> invalid, argmax = 0
    } else {
        uint32_t best = kv.x; int bsp = 0;
        if (kv.y > best) { best = kv.y; bsp = 1; }
        if (kv.z > best) { best = kv.z; bsp = 2; }
        if (kv.w > best) { best = kv.w; bsp = 3; }
        const uint32_t bt = best & ~63u;
        const uint32_t s0 = (bsp == 0) ? 0u : (kv.x & ~63u);
        const uint32_t s1 = (bsp == 1) ? 0u : (kv.y & ~63u);
        const uint32_t s2 = (bsp == 2) ? 0u : (kv.z & ~63u);
        const uint32_t s3 = (bsp == 3) ? 0u : (kv.w & ~63u);
        const uint32_t sec = max(max(s0, s1), max(s2, s3));
        float a1 = (bx.z - bx.x) * (bx.w - bx.y); opaquef(a1);
        if ((bt != 0u) && (bt - sec) <= 64u) {
            // ambiguous across splits: exact 4-way, split ascending, strict >
            float qb = -1.0f; midx = 0;
            #pragma unroll
            for (int sp = 0; sp < SPLIT; ++sp) {
                const uint32_t k = (sp == 0) ? kv.x : (sp == 1) ? kv.y
                                 : (sp == 2) ? kv.z : kv.w;
                const int m = sp * MSUB + (63 - (int)(k & 63u));
                float4 g = gb4[m];
                float a2 = (g.z - g.x) * (g.w - g.y); opaquef(a2);
                float ih = fmaxf(fminf(bx.z, g.z) - fmaxf(bx.x, g.x), 0.0f);
                float iw = fmaxf(fminf(bx.w, g.w) - fmaxf(bx.y, g.y), 0.0f);
                float inter = ih * iw; opaquef(inter);
                float uni = (a1 + a2) - inter;
                float q = (uni > 0.0f) ? (inter / uni) : 0.0f;
                if (q > qb) { qb = q; midx = m; }
            }
            cls = (qb >= 0.5f) ? 1 : 0;
        } else {
            midx = bsp * MSUB + (63 - (int)(best & 63u));
            float4 g = gb4[midx];
            float a2 = (g.z - g.x) * (g.w - g.y); opaquef(a2);
            float ih = fmaxf(fminf(bx.z, g.z) - fmaxf(bx.x, g.x), 0.0f);
            float iw = fmaxf(fminf(bx.w, g.w) - fmaxf(bx.y, g.y), 0.0f);
            float inter = ih * iw; opaquef(inter);
            float uni = (a1 + a2) - inter;     // numpy op order/rounding
            float q = (uni > 0.0f) ? (inter / uni) : 0.0f;   // exact reference
            cls = (q >= 0.5f) ? 1 : 0;         // searchsorted([0,.5,.5], right)
        }
    }
    ((uint16_t*)keys)[((size_t)b * LL + l) * 8] = (uint16_t)(cls | (midx << 2));
}

// ---------------- scans ----------------
__device__ __forceinline__ int block_exscan_fast(int v, int* wt, int tid)
{
    const int lane = tid & 63, w = tid >> 6;
    int x = v;
    #pragma unroll
    for (int off = 1; off < 64; off <<= 1) {
        int y = __shfl_up(x, off);
        if (lane >= off) x += y;
    }
    if (lane == 63) wt[w] = x;
    __syncthreads();
    if (tid < 64) {
        int t = (tid < 16) ? wt[tid] : 0;
        #pragma unroll
        for (int off = 1; off < 16; off <<= 1) {
            int y = __shfl_up(t, off);
            if (tid >= off) t += y;
        }
        if (tid < 16) wt[tid] = t;
    }
    __syncthreads();
    return ((w > 0) ? wt[w - 1] : 0) + x - v;
}

__device__ __forceinline__ int block_exscan_seg4(int v, int* wt, int tid)
{
    const int lane = tid & 63, w = tid >> 6;
    int x = v;
    #pragma unroll
    for (int off = 1; off < 64; off <<= 1) {
        int y = __shfl_up(x, off);
        if (lane >= off) x += y;
    }
    if (lane == 63) wt[w] = x;
    __syncthreads();
    if (tid < 16) {
        int t = wt[tid];
        #pragma unroll
        for (int off = 1; off < 4; off <<= 1) {
            int y = __shfl_up(t, off);
            if ((tid & 3) >= off) t += y;
        }
        wt[tid] = t;
    }
    __syncthreads();
    return (((w & 3) > 0) ? wt[w - 1] : 0) + x - v;
}

// ---------------- kernel 2: per-batch sampling + gather --------------------
// s_pk bit layout: [1:0] cls, [9:2] matched gt idx, [15] sel flag
__global__ __launch_bounds__(T2) void sample_kernel(
    const float* __restrict__ boxes, const float* __restrict__ gt,
    const int* __restrict__ gtc, const float* __restrict__ rnd,
    const uint32_t* __restrict__ keys, float* __restrict__ out)
{
    __shared__ uint32_t s_key[LL];
    __shared__ uint16_t s_pk[LL];
    __shared__ int s_hist[512];
    __shared__ int s_warp[16];
    __shared__ int s_idx[NSAMP];
    __shared__ int s_sb[8];
    const int b = blockIdx.x, tid = threadIdx.x, lane = tid & 63;
    const float4* bb4 = (const float4*)(boxes + (size_t)b * NN * 4);
    const float4* gb4 = (const float4*)(gt + (size_t)b * MM * 4);

    if (tid == 0) s_sb[0] = 0;
    __syncthreads();

    int loc = 0;
    for (int l = tid; l < LL; l += T2) {
        s_key[l] = __float_as_uint(rnd[(size_t)b * LL + l]);
        uint16_t p = ((const uint16_t*)keys)[((size_t)b * LL + l) * 8];
        s_pk[l] = p;
        int c = p & 3;
        loc += (c == 0) ? 1 : ((c == 1) ? 0x10000 : 0);
    }
    #pragma unroll
    for (int off = 32; off; off >>= 1) loc += __shfl_xor(loc, off);
    if (lane == 0) atomicAdd(&s_sb[0], loc);
    __syncthreads();
    const int Nn = s_sb[0] & 0xFFFF, P = s_sb[0] >> 16;

    const int posK = (P < MAXPOS) ? P : MAXPOS;
    const int negK = NSAMP - posK;
    const bool negRad = (Nn > negK);
    const bool posRad = (P > MAXPOS);

    uint32_t prefix0 = 0, prefix1 = 0;
    int rem0 = negK, rem1 = MAXPOS;
    if (negRad || posRad) {
        for (int round = 0; round < 4; ++round) {
            const int shift = 24 - 8 * round;
            if (tid < 512) s_hist[tid] = 0;
            __syncthreads();
            const uint32_t pmask = (round == 0) ? 0u : (0xFFFFFFFFu << (shift + 8));
            for (int l = tid; l < LL; l += T2) {
                const uint32_t k = s_key[l];
                const int c = s_pk[l] & 3;
                bool doit = (c == 0) ? (negRad && ((k & pmask) == prefix0))
                          : (c == 1) ? (posRad && ((k & pmask) == prefix1))
                          : false;
                if (doit) atomicAdd(&s_hist[(c << 8) | ((k >> shift) & 255)], 1);
            }
            __syncthreads();
            int h = 0;
            if (tid < 512) h = s_hist[(tid & 0x100) | (255 - (tid & 255))];
            const int above = block_exscan_seg4(h, s_warp, tid);
            if (tid < 512) {
                const int c = tid >> 8;
                const int rem = c ? rem1 : rem0;
                const bool act = c ? posRad : negRad;
                if (act && above < rem && above + h >= rem) {
                    s_sb[4 + c * 2] = 255 - (tid & 255);
                    s_sb[5 + c * 2] = above;
                }
            }
            __syncthreads();
            if (negRad) { prefix0 |= ((uint32_t)s_sb[4]) << shift; rem0 -= s_sb[5]; }
            if (posRad) { prefix1 |= ((uint32_t)s_sb[6]) << shift; rem1 -= s_sb[7]; }
            __syncthreads();
        }
    }
    const uint32_t thr0 = negRad ? prefix0 : 0u;  const int r0 = negRad ? rem0 : LL;
    const uint32_t thr1 = posRad ? prefix1 : 0u;  const int r1 = posRad ? rem1 : LL;

    const int lo = tid * CH, hi = (lo + CH < LL) ? (lo + CH) : LL;
    int nt = 0;
    for (int l = lo; l < hi; ++l) {
        const int c = s_pk[l] & 3;
        const uint32_t k = s_key[l];
        if (c == 0) { if (k == thr0) nt += 1; }
        else if (c == 1) { if (k == thr1) nt += 0x10000; }
    }
    const int basep = block_exscan_fast(nt, s_warp, tid);
    int base0 = basep & 0xFFFF, base1 = basep >> 16;
    for (int l = lo; l < hi; ++l) {
        const int c = s_pk[l] & 3;
        if (c > 1) continue;
        const uint32_t k = s_key[l];
        const uint32_t thr = c ? thr1 : thr0;
        bool sel = (k > thr);
        if (k == thr) {
            if (c == 0) { sel = (base0 < r0); ++base0; }
            else        { sel = (base1 < r1); ++base1; }
        }
        if (sel) s_pk[l] |= 0x8000;
    }
    __syncthreads();

    int cnt = 0;
    for (int l = lo; l < hi; ++l) cnt += (s_pk[l] & 0x8000) ? 1 : 0x10000;
    const int pb = block_exscan_fast(cnt, s_warp, tid);
    const int S = s_warp[15] & 0xFFFF;
    int bs = pb & 0xFFFF, bu = (pb >> 16) + S;
    for (int l = lo; l < hi; ++l) {
        if (s_pk[l] & 0x8000) { if (bs < NSAMP) s_idx[bs] = l; ++bs; }
        else                  { if (bu < NSAMP) s_idx[bu] = l; ++bu; }
    }
    __syncthreads();

    if (tid < NSAMP) {
        const int l = s_idx[tid];
        float4 bx = (l < NN) ? bb4[l] : gb4[l - NN];
        const int p = s_pk[l];
        const int c = p & 3, mi = (p >> 2) & 0xFF;
        const bool bg = (c != 1);          // background = matched_val < 0.5
        float4 gb = make_float4(0.f, 0.f, 0.f, 0.f);
        int cl = 0, si = -1;
        if (!bg) {
            gb = gb4[mi];
            cl = gtc[(size_t)b * MM + mi];
            si = mi;
        }
        const size_t rk = (size_t)b * NSAMP + tid;
        ((float4*)out)[rk] = bx;                                   // rois
        ((float4*)(out + (size_t)BB * NSAMP * 4))[rk] = gb;        // sampled_gt_boxes
        out[(size_t)2 * BB * NSAMP * 4 + rk] = (float)cl;          // classes
        out[(size_t)2 * BB * NSAMP * 4 + (size_t)BB * NSAMP + rk] = (float)si; // indices
    }
}

extern "C" void kernel_launch(void* const* d_in, const int* in_sizes, int n_in,
                              void* d_out, int out_size, void* d_ws, size_t ws_size,
                              hipStream_t stream)
{
    const float* boxes = (const float*)d_in[0];   // [32,8000,4] f32
    const float* gt    = (const float*)d_in[1];   // [32,256,4]  f32
    const int*   gtc   = (const int*)  d_in[2];   // [32,256]    i32
    const float* rnd   = (const float*)d_in[3];   // [32,8256]   f32
    float* out = (float*)d_out;
    uint32_t* keys = (uint32_t*)d_ws;             // BB*LL*SPLIT*4 = 4.22 MB

    dim3 g1((LL + MT * 2 - 1) / (MT * 2), BB, SPLIT);   // 33,32,4 = 4224 blocks
    match_split_kernel<<<g1, MT, 0, stream>>>(boxes, gt, keys);
    dim3 g2((LL + 255) / 256, BB);                      // 33,32
    merge2_kernel<<<g2, 256, 0, stream>>>(boxes, gt, keys);
    sample_kernel<<<BB, T2, 0, stream>>>(boxes, gt, gtc, rnd, keys, out);
}